// Round 6
// baseline (196.850 us; speedup 1.0000x reference)
//
#include <hip/hip_runtime.h>
#include <cstdint>
#include <cstddef>

typedef __bf16 bf16;
typedef __bf16 bf16x8 __attribute__((ext_vector_type(8)));
typedef __bf16 bf16x4v __attribute__((ext_vector_type(4)));
typedef float  f32x4  __attribute__((ext_vector_type(4)));

#define MFMA(a, b, c) __builtin_amdgcn_mfma_f32_16x16x32_bf16((a), (b), (c), 0, 0, 0)

typedef __attribute__((address_space(3))) unsigned int  lds_u32;
typedef __attribute__((address_space(1))) unsigned int glob_u32;

// B=4, N=1024, DIM=768, HEADS=12, DIM_HEAD=64, INNER=768
// kScl = SCALE*0.5 = 0.5/sqrt(768); c2 = kScl*log2(e), folded into qcat.

// ---------------------------------------------------------------------------
// fp32 -> bf16 convert for x and pos in one launch. grid 6144 x 256.
// ---------------------------------------------------------------------------
__global__ void k_cvt2(const float* __restrict__ x, const float* __restrict__ pos,
                       bf16* __restrict__ xb, bf16* __restrict__ posb) {
    int i = blockIdx.x * 256 + threadIdx.x;
    const float* in = x; bf16* out = xb;
    if (i >= 786432) { i -= 786432; in = pos; out = posb; }
    float4 v = reinterpret_cast<const float4*>(in)[i];
    bf16x4v o; o[0] = (bf16)v.x; o[1] = (bf16)v.y; o[2] = (bf16)v.z; o[3] = (bf16)v.w;
    reinterpret_cast<bf16x4v*>(out)[i] = o;
}

// ---------------------------------------------------------------------------
// Transposing convert for all 3 weights in one launch: in[k][n] fp32 (k=768)
// -> out[n][768] bf16. grid (144, 24) x 256.
// ---------------------------------------------------------------------------
__global__ void k_tr(const float* __restrict__ w_qkv, const float* __restrict__ w_qk_pos,
                     const float* __restrict__ w_out,
                     bf16* __restrict__ wqkvT, bf16* __restrict__ wqkposT,
                     bf16* __restrict__ woutT) {
    __shared__ float t[32][33];
    int bx = blockIdx.x;
    const float* in; bf16* out; int N;
    if (bx < 72)       { in = w_qkv;    out = wqkvT;   N = 2304; }
    else if (bx < 120) { in = w_qk_pos; out = wqkposT; N = 1536; bx -= 72; }
    else               { in = w_out;    out = woutT;   N = 768;  bx -= 120; }
    const int n0 = bx * 32, k0 = blockIdx.y * 32;
    const int tx = threadIdx.x & 31, ty = threadIdx.x >> 5;
#pragma unroll
    for (int r = 0; r < 32; r += 8)
        t[ty + r][tx] = in[(size_t)(k0 + ty + r) * N + n0 + tx];
    __syncthreads();
#pragma unroll
    for (int r = 0; r < 32; r += 8)
        out[(size_t)(n0 + ty + r) * 768 + k0 + tx] = (bf16)t[tx][ty + r];
}

// ---------------------------------------------------------------------------
// Merged GEMM for qkv (mode 0) and qk_pos (mode 1). 128x128 tile, glds
// double-buffered, XOR-swizzled LDS, XCD-aware 1D grid 960.
// qcat stores are pre-scaled by c2 = 0.5/sqrt(768)*log2(e) so attention can
// use exp2 directly on raw MFMA scores.
// ---------------------------------------------------------------------------
__launch_bounds__(256, 3)
__global__ void k_gemm12(const bf16* __restrict__ xb, const bf16* __restrict__ posb,
                         const bf16* __restrict__ wqkvT, const bf16* __restrict__ wqkposT,
                         bf16* __restrict__ qcat, bf16* __restrict__ kcat,
                         bf16* __restrict__ vT) {
    __shared__ bf16 lA[2][128][32];
    __shared__ bf16 lB[2][128][32];

    const int tid  = threadIdx.x;
    const int lane = tid & 63, wave = tid >> 6;
    const int quad = lane >> 4, col = lane & 15;
    const int sw2  = (col >> 1) & 3;
    const int wm = (wave >> 1) * 64, wn = (wave & 1) * 64;

    const int fid = blockIdx.x;
    const int xcd = fid & 7, s = fid >> 3;
    const int sx = s % 15, sy = s / 15;
    int bx = (xcd & 1) * 15 + sx;
    const int by = (xcd >> 1) * 8 + sy;

    int mode, nBase;
    const bf16 *A, *BT;
    if (bx < 18) { mode = 0; A = xb;   BT = wqkvT;   nBase = bx * 128; }
    else         { mode = 1; A = posb; BT = wqkposT; nBase = (bx - 18) * 128; }
    const int mBase = by * 128;

    const bf16* Ap = A  + (size_t)mBase * 768;
    const bf16* Bp = BT + (size_t)nBase * 768;

#define STAGE12(buf, k0)                                                        \
    _Pragma("unroll")                                                           \
    for (int j = 0; j < 2; ++j) {                                               \
        int idx = (wave * 2 + j) * 64 + lane;                                   \
        int row = idx >> 2, c = (idx & 3) ^ ((row >> 1) & 3);                   \
        __builtin_amdgcn_global_load_lds(                                       \
            (const glob_u32*)(Ap + (size_t)row * 768 + (k0) + c * 8),           \
            (lds_u32*)((char*)&lA[buf][0][0] + (wave * 2 + j) * 1024), 16, 0, 0);\
        __builtin_amdgcn_global_load_lds(                                       \
            (const glob_u32*)(Bp + (size_t)row * 768 + (k0) + c * 8),           \
            (lds_u32*)((char*)&lB[buf][0][0] + (wave * 2 + j) * 1024), 16, 0, 0);\
    }

    f32x4 acc[4][4];
#pragma unroll
    for (int mi = 0; mi < 4; ++mi)
#pragma unroll
        for (int ni = 0; ni < 4; ++ni) acc[mi][ni] = f32x4{0.f, 0.f, 0.f, 0.f};

    STAGE12(0, 0)
    for (int it = 0; it < 24; ++it) {
        const int cur = it & 1, nxt = cur ^ 1;
        __syncthreads();
        if (it < 23) STAGE12(nxt, (it + 1) * 32)

        bf16x8 af[4], bfg[4];
#pragma unroll
        for (int mi = 0; mi < 4; ++mi)
            af[mi]  = *(const bf16x8*)&lA[cur][wm + mi * 16 + col][(quad ^ sw2) * 8];
#pragma unroll
        for (int ni = 0; ni < 4; ++ni)
            bfg[ni] = *(const bf16x8*)&lB[cur][wn + ni * 16 + col][(quad ^ sw2) * 8];
#pragma unroll
        for (int mi = 0; mi < 4; ++mi)
#pragma unroll
            for (int ni = 0; ni < 4; ++ni)
                acc[mi][ni] = MFMA(af[mi], bfg[ni], acc[mi][ni]);
    }
#undef STAGE12

    const float c2s = 0.018042195912f * 1.44269504089f;
    const int bb = mBase >> 10;
    const int sr0 = (mBase & 1023) + wm + quad * 4;
#pragma unroll
    for (int ni = 0; ni < 4; ++ni) {
        const int nb = nBase + wn + ni * 16;
        const int which = (mode == 0) ? (nb >= 1536 ? 2 : (nb >= 768 ? 1 : 0))
                                      : (nb >= 768 ? 1 : 0);
        const int rem = nb - which * 768;
        const int hh = rem >> 6, dd0 = rem & 63;
        const size_t hb = (size_t)(bb * 12 + hh);
        if (mode == 0 && which == 2) {
            bf16* dstv = vT + (hb * 64 + dd0 + col) * 1024 + sr0;
#pragma unroll
            for (int mi = 0; mi < 4; ++mi) {
                bf16x4v pk;
#pragma unroll
                for (int r = 0; r < 4; ++r) pk[r] = (bf16)acc[mi][ni][r];
                *(bf16x4v*)(dstv + mi * 16) = pk;
            }
        } else {
            const float scl = (which == 0) ? c2s : 1.0f;
            bf16* dstq = (which == 0 ? qcat : kcat)
                       + (hb * 1024 + sr0) * 128 + (mode == 1 ? 64 : 0) + dd0 + col;
#pragma unroll
            for (int mi = 0; mi < 4; ++mi)
#pragma unroll
                for (int r = 0; r < 4; ++r)
                    dstq[(size_t)(mi * 16 + r) * 128] = (bf16)(acc[mi][ni][r] * scl);
        }
    }
}

// ---------------------------------------------------------------------------
// Flash attention v3: register-resident, LDS-free/barrier-free K-loop.
// Block = (64 q-rows, unit); wave w owns kv-slice it*64 + w*16 each iter.
// Q (64 rows x 128d, pre-scaled by c2) held in registers as B-fragments.
// S^T = K*Q^T per kv-slice: C-layout (kv=quad*4+r, q=col) IS the B-fragment
// layout for O^T = V^T * P^T -- P goes MFMA->exp2->MFMA entirely in regs.
// Two iterations pair into one K=32 PV (kv order inside the 32-chunk is a
// free permutation; V loads use the same interleave).
// LDS only for the final cross-wave O/l reduction.
// 1D grid 768, XCD-pinned as in round 5.
// ---------------------------------------------------------------------------
__launch_bounds__(256, 2)
__global__ void k_attn(const bf16* __restrict__ qcat, const bf16* __restrict__ kcat,
                       const bf16* __restrict__ vT, bf16* __restrict__ attn_out) {
    __shared__ float lRed[4][64][68];   // [wave][q][vd] (+4 pad)  69632 B
    __shared__ float lS[16][64];        // [wave*4+quad][q] partial denominators
    __shared__ float lSinv[64];

    const int tid  = threadIdx.x;
    const int lane = tid & 63, wave = tid >> 6;
    const int quad = lane >> 4, col = lane & 15;

    const int fid = blockIdx.x;
    const int xcd = fid & 7, s = fid >> 3;
    const int qt = s & 15;
    const int unit = (s >> 4) * 8 + xcd;      // == b*12+h
    const int b = unit / 12, h = unit % 12;

    const bf16* Qb = qcat + (size_t)unit * 1024 * 128;
    const bf16* Kb = kcat + (size_t)unit * 1024 * 128;
    const bf16* Vb = vT   + (size_t)unit * 64 * 1024;

    // Q B-fragments (reused all 16 iterations): q = qt*64+nt*16+col
    bf16x8 qb[4][4];
#pragma unroll
    for (int nt = 0; nt < 4; ++nt) {
        const bf16* qrow = Qb + (size_t)(qt * 64 + nt * 16 + col) * 128;
#pragma unroll
        for (int f = 0; f < 4; ++f)
            qb[nt][f] = *(const bf16x8*)(qrow + f * 32 + quad * 8);
    }

    f32x4 o[4][4];                       // o[vt][nt] = O^T tile (vd, q)
#pragma unroll
    for (int vt = 0; vt < 4; ++vt)
#pragma unroll
        for (int nt = 0; nt < 4; ++nt) o[vt][nt] = f32x4{0.f, 0.f, 0.f, 0.f};
    float ps[4] = {0.f, 0.f, 0.f, 0.f};

    const int kvw = wave * 16;

    for (int itp = 0; itp < 8; ++itp) {
        const int kvA = itp * 128 + kvw;
        const int kvB = kvA + 64;

        // issue all global loads for the pair up front (L2-resident, XCD-local)
        bf16x8 kfA[4], kfB[4];
#pragma unroll
        for (int f = 0; f < 4; ++f) {
            kfA[f] = *(const bf16x8*)(Kb + (size_t)(kvA + col) * 128 + f * 32 + quad * 8);
            kfB[f] = *(const bf16x8*)(Kb + (size_t)(kvB + col) * 128 + f * 32 + quad * 8);
        }
        bf16x8 vf[4];
#pragma unroll
        for (int vt = 0; vt < 4; ++vt) {
            bf16x4v va = *(const bf16x4v*)(Vb + (size_t)(vt * 16 + col) * 1024 + kvA + quad * 4);
            bf16x4v vb = *(const bf16x4v*)(Vb + (size_t)(vt * 16 + col) * 1024 + kvB + quad * 4);
#pragma unroll
            for (int i = 0; i < 4; ++i) { vf[vt][i] = va[i]; vf[vt][4 + i] = vb[i]; }
        }

        bf16x8 pbf[4];
        // half A: S^T = K_A * Q^T, p = exp2(s)
#pragma unroll
        for (int nt = 0; nt < 4; ++nt) {
            f32x4 st = f32x4{0.f, 0.f, 0.f, 0.f};
#pragma unroll
            for (int f = 0; f < 4; ++f) st = MFMA(kfA[f], qb[nt][f], st);
            float p0 = exp2f(st[0]), p1 = exp2f(st[1]);
            float p2 = exp2f(st[2]), p3 = exp2f(st[3]);
            ps[nt] += (p0 + p1) + (p2 + p3);
            pbf[nt][0] = (bf16)p0; pbf[nt][1] = (bf16)p1;
            pbf[nt][2] = (bf16)p2; pbf[nt][3] = (bf16)p3;
        }
        // half B
#pragma unroll
        for (int nt = 0; nt < 4; ++nt) {
            f32x4 st = f32x4{0.f, 0.f, 0.f, 0.f};
#pragma unroll
            for (int f = 0; f < 4; ++f) st = MFMA(kfB[f], qb[nt][f], st);
            float p0 = exp2f(st[0]), p1 = exp2f(st[1]);
            float p2 = exp2f(st[2]), p3 = exp2f(st[3]);
            ps[nt] += (p0 + p1) + (p2 + p3);
            pbf[nt][4] = (bf16)p0; pbf[nt][5] = (bf16)p1;
            pbf[nt][6] = (bf16)p2; pbf[nt][7] = (bf16)p3;
        }
        // PV: O^T += V^T * P^T  (B-frag == pbf by construction)
#pragma unroll
        for (int vt = 0; vt < 4; ++vt)
#pragma unroll
            for (int nt = 0; nt < 4; ++nt)
                o[vt][nt] = MFMA(vf[vt], pbf[nt], o[vt][nt]);
    }

    // cross-wave reduction: o[vt][nt] lives at (vd=vt*16+quad*4+r, q=nt*16+col)
#pragma unroll
    for (int vt = 0; vt < 4; ++vt)
#pragma unroll
        for (int nt = 0; nt < 4; ++nt)
            *(f32x4*)&lRed[wave][nt * 16 + col][vt * 16 + quad * 4] = o[vt][nt];
#pragma unroll
    for (int nt = 0; nt < 4; ++nt)
        lS[wave * 4 + quad][nt * 16 + col] = ps[nt];
    __syncthreads();

    if (tid < 64) {
        float t = 0.f;
#pragma unroll
        for (int w = 0; w < 16; ++w) t += lS[w][tid];
        lSinv[tid] = 1.f / t;
    }
    __syncthreads();

    // combine 4 wave-partials, normalize, store. 1024 f32x4 chunks / 4 per thread
#pragma unroll
    for (int cix = 0; cix < 4; ++cix) {
        int c = cix * 256 + tid;
        int q = c >> 4, v4 = (c & 15) * 4;
        f32x4 acc = *(const f32x4*)&lRed[0][q][v4];
        acc += *(const f32x4*)&lRed[1][q][v4];
        acc += *(const f32x4*)&lRed[2][q][v4];
        acc += *(const f32x4*)&lRed[3][q][v4];
        float inv = lSinv[q];
        bf16x4v pk;
#pragma unroll
        for (int i = 0; i < 4; ++i) pk[i] = (bf16)(acc[i] * inv);
        *(bf16x4v*)(attn_out + ((size_t)b * 1024 + qt * 64 + q) * 768 + h * 64 + v4) = pk;
    }
}

// ---------------------------------------------------------------------------
// Out projection: out[4096][768] = aout @ woutT^T + bias (fp32 out)
// 128m x 64n tiles, glds double-buffered. 1D grid 384, XCD-aware 6bx x 8by.
// ---------------------------------------------------------------------------
__launch_bounds__(256, 3)
__global__ void k_gemm_out(const bf16* __restrict__ aout, const bf16* __restrict__ woutT,
                           const float* __restrict__ bias, float* __restrict__ out) {
    __shared__ bf16 lA[2][128][32];
    __shared__ bf16 lB[2][64][32];

    const int tid  = threadIdx.x;
    const int lane = tid & 63, wave = tid >> 6;
    const int quad = lane >> 4, col = lane & 15;
    const int sw2  = (col >> 1) & 3;
    const int wm = (wave >> 1) * 64, wn = (wave & 1) * 32;

    const int fid = blockIdx.x;
    const int xcd = fid & 7, s = fid >> 3;
    const int sx = s % 6, sy = s / 6;
    const int bx = (xcd & 1) * 6 + sx;
    const int by = (xcd >> 1) * 8 + sy;

    const int mBase = by * 128, nBase = bx * 64;

    const bf16* Ap = aout  + (size_t)mBase * 768;
    const bf16* Bp = woutT + (size_t)nBase * 768;

#define STAGE_O(buf, k0)                                                        \
    _Pragma("unroll")                                                           \
    for (int j = 0; j < 2; ++j) {                                               \
        int idx = (wave * 2 + j) * 64 + lane;                                   \
        int row = idx >> 2, c = (idx & 3) ^ ((row >> 1) & 3);                   \
        __builtin_amdgcn_global_load_lds(                                       \
            (const glob_u32*)(Ap + (size_t)row * 768 + (k0) + c * 8),           \
            (lds_u32*)((char*)&lA[buf][0][0] + (wave * 2 + j) * 1024), 16, 0, 0);\
    }                                                                           \
    {                                                                           \
        int idx = wave * 64 + lane;                                             \
        int row = idx >> 2, c = (idx & 3) ^ ((row >> 1) & 3);                   \
        __builtin_amdgcn_global_load_lds(                                       \
            (const glob_u32*)(Bp + (size_t)row * 768 + (k0) + c * 8),           \
            (lds_u32*)((char*)&lB[buf][0][0] + wave * 1024), 16, 0, 0);         \
    }

    f32x4 acc[4][2];
#pragma unroll
    for (int mi = 0; mi < 4; ++mi)
#pragma unroll
        for (int ni = 0; ni < 2; ++ni) acc[mi][ni] = f32x4{0.f, 0.f, 0.f, 0.f};

    STAGE_O(0, 0)
    for (int it = 0; it < 24; ++it) {
        const int cur = it & 1, nxt = cur ^ 1;
        __syncthreads();
        if (it < 23) STAGE_O(nxt, (it + 1) * 32)

        bf16x8 af[4], bfg[2];
#pragma unroll
        for (int mi = 0; mi < 4; ++mi)
            af[mi]  = *(const bf16x8*)&lA[cur][wm + mi * 16 + col][(quad ^ sw2) * 8];
#pragma unroll
        for (int ni = 0; ni < 2; ++ni)
            bfg[ni] = *(const bf16x8*)&lB[cur][wn + ni * 16 + col][(quad ^ sw2) * 8];
#pragma unroll
        for (int mi = 0; mi < 4; ++mi)
#pragma unroll
            for (int ni = 0; ni < 2; ++ni)
                acc[mi][ni] = MFMA(af[mi], bfg[ni], acc[mi][ni]);
    }
#undef STAGE_O

#pragma unroll
    for (int mi = 0; mi < 4; ++mi)
#pragma unroll
        for (int ni = 0; ni < 2; ++ni)
#pragma unroll
            for (int r = 0; r < 4; ++r) {
                int m = mBase + wm + mi * 16 + quad * 4 + r;
                int n = nBase + wn + ni * 16 + col;
                out[(size_t)m * 768 + n] = acc[mi][ni][r] + bias[n];
            }
}

// ---------------------------------------------------------------------------
// Workspace layout (bytes): total 57409536 B
// ---------------------------------------------------------------------------
extern "C" void kernel_launch(void* const* d_in, const int* in_sizes, int n_in,
                              void* d_out, int out_size, void* d_ws, size_t ws_size,
                              hipStream_t stream) {
    const float* x        = (const float*)d_in[0];
    const float* pos      = (const float*)d_in[1];
    const float* w_qkv    = (const float*)d_in[2];
    const float* w_qk_pos = (const float*)d_in[3];
    const float* w_out    = (const float*)d_in[4];
    const float* b_out    = (const float*)d_in[5];
    float* out = (float*)d_out;

    char* ws = (char*)d_ws;
    bf16* xb      = (bf16*)(ws);
    bf16* posb    = (bf16*)(ws + 6291456);
    bf16* wqkvT   = (bf16*)(ws + 12582912);
    bf16* wqkposT = (bf16*)(ws + 16121856);
    bf16* woutT   = (bf16*)(ws + 18481152);
    bf16* qcat    = (bf16*)(ws + 19660800);
    bf16* kcat    = (bf16*)(ws + 32243712);
    bf16* vT      = (bf16*)(ws + 44826624);
    bf16* aout    = (bf16*)(ws + 51118080);

    k_cvt2<<<6144, 256, 0, stream>>>(x, pos, xb, posb);
    k_tr<<<dim3(144, 24), 256, 0, stream>>>(w_qkv, w_qk_pos, w_out, wqkvT, wqkposT, woutT);
    k_gemm12<<<960, 256, 0, stream>>>(xb, posb, wqkvT, wqkposT, qcat, kcat, vT);
    k_attn<<<768, 256, 0, stream>>>(qcat, kcat, vT, aout);
    k_gemm_out<<<384, 256, 0, stream>>>(aout, woutT, b_out, out);
}